// Round 5
// baseline (6146.211 us; speedup 1.0000x reference)
//
#include <hip/hip_runtime.h>
#include <stdint.h>

// ---------------------------------------------------------------------------
// Persistent-kernel LSTM (relu g-gate, h = o*c, no tanh).
// B=128, S=1024, I=256, H=512, O=10.
//
// R5: guaranteed XCD-pure groups + fragment-order payload.
//  * 512 blocks (2/CU guaranteed resident). Rendezvous publishes XCC_IDs;
//    greedy same-XCD chunks of 32 form 8 groups for ANY placement
//    (sum floor(cnt/32) >= 9). Surplus blocks exit. No sc1 fallback.
//  * h payload stored in MFMA-A fragment order [kb][lane][8]: consumers
//    load A-frags straight to registers (16 coalesced dwordx4), no h LDS,
//    no 8-way bank conflicts. Freshness via W-slot rotation (addresses
//    never re-read before W steps of L1 turnover) — plain loads.
//  * x tile in LDS also fragment-order -> conflict-free ds_read_b128.
//  * Flags: producer plain-stores h -> vmcnt(0) -> barrier -> asm flag
//    store (same XCD L2); consumer polls via global_atomic_add(0) sc0
//    (atomics execute at TCC, never stale-L1).
// ---------------------------------------------------------------------------

#define GROUPS 8
#define BC     16
#define S_LEN  1024
#define I_DIM  256
#define H_DIM  512
#define NBLK   512
#define FSTRIDE 16                    // flag stride in ints (64 B)
#define PAYG   (BC * H_DIM)           // 8192 shorts per group per slot
#define PAYSLOT (GROUPS * PAYG)       // shorts per rotation slot

typedef float f32x4 __attribute__((ext_vector_type(4)));
typedef short s16x8 __attribute__((ext_vector_type(8)));

__device__ __forceinline__ unsigned short f2bf(float f) {
  unsigned u = __float_as_uint(f);
  u += 0x7fffu + ((u >> 16) & 1u);   // RNE
  return (unsigned short)(u >> 16);
}
__device__ __forceinline__ float bf2f(unsigned short h) {
  return __uint_as_float(((unsigned)h) << 16);
}
__device__ __forceinline__ float sigf(float x) { return 1.0f / (1.0f + __expf(-x)); }

// flag poll: atomic executes at TCC (L2) -> always fresh, XCD-local latency
__device__ __forceinline__ int poll_local(uint64_t a) {
  int v;
  asm volatile("global_atomic_add %0, %1, %2, off sc0\n\ts_waitcnt vmcnt(0)"
               : "=v"(v) : "v"(a), "v"(0) : "memory");
  return v;
}
// device-scope ops for the one-time rendezvous only
__device__ __forceinline__ int ld_sc1(uint64_t a) {
  int v;
  asm volatile("global_load_dword %0, %1, off sc1\n\ts_waitcnt vmcnt(0)"
               : "=v"(v) : "v"(a) : "memory");
  return v;
}
__device__ __forceinline__ void st_sc1(uint64_t a, int v) {
  asm volatile("global_store_dword %0, %1, off sc1" :: "v"(a), "v"(v) : "memory");
}
__device__ __forceinline__ void st_flag(uint64_t a, int v) {
  asm volatile("global_store_dword %0, %1, off" :: "v"(a), "v"(v) : "memory");
}
__device__ __forceinline__ void drain_vm() {
  asm volatile("s_waitcnt vmcnt(0)" ::: "memory");
}

__global__ __launch_bounds__(256, 2)
void lstm_persistent(const float* __restrict__ x,
                     const float* __restrict__ Wih,
                     const float* __restrict__ Whh,
                     const float* __restrict__ bih,
                     const float* __restrict__ bhh,
                     const float* __restrict__ fcw,
                     const float* __restrict__ fcb,
                     float* __restrict__ out,
                     int* __restrict__ arrive,           // [1], zeroed
                     int* __restrict__ table,            // [NBLK]
                     int* __restrict__ flags,            // [GROUPS][32][FSTRIDE]
                     unsigned short* __restrict__ hpay,  // [W][GROUPS][PAYG]
                     int wmask)
{
  __shared__ __align__(16) unsigned short x_s[2][8][512];  // fragment-order x
  __shared__ __align__(16) float gates[4][BC][18];
  __shared__ int tbl[NBLK];
  __shared__ int s_grp, s_slot, s_abort;

  const int tid  = threadIdx.x;
  const int wave = tid >> 6;        // gate section 0..3 (i,f,g,o)
  const int lane = tid & 63;
  const int q    = lane >> 4;
  const int l15  = lane & 15;
  const int bid  = blockIdx.x;

  // ---- rendezvous: publish my XCD, wait for all NBLK, read the table ----
  const int xcd = __builtin_amdgcn_s_getreg((31u << 11) | 20) & 7;  // HW_REG_XCC_ID
  if (tid == 0) {
    st_sc1((uint64_t)&table[bid], xcd);
    drain_vm();
    atomicAdd(arrive, 1);
    int spins = 0;
    while (atomicAdd(arrive, 0) < NBLK && spins < (1 << 22)) {
      __builtin_amdgcn_s_sleep(8);
      ++spins;
    }
  }
  __syncthreads();
  tbl[tid]       = ld_sc1((uint64_t)&table[tid]) & 7;
  tbl[tid + 256] = ld_sc1((uint64_t)&table[tid + 256]) & 7;
  __syncthreads();
  if (tid == 0) {
    int cnt[8] = {0, 0, 0, 0, 0, 0, 0, 0};
    int myrank = 0;
    for (int j = 0; j < NBLK; ++j) {
      if (j == bid) myrank = cnt[xcd];
      cnt[tbl[j]]++;
    }
    int base = 0, grp = -1, slot = 0;
    for (int k = 0; k < 8; ++k) {
      const int gk = cnt[k] >> 5;          // whole chunks of 32 on XCD k
      if (k == xcd) {
        const int chunk = myrank >> 5;
        if (chunk < gk && base + chunk < 8) { grp = base + chunk; slot = myrank & 31; }
      }
      base += gk;
    }
    s_grp = grp; s_slot = slot; s_abort = 0;
  }
  __syncthreads();
  const int g    = s_grp;
  const int slot = s_slot;
  if (g < 0) return;                       // surplus block

  // ---- persistent weight fragments (B-frag: lane holds B[k=q*8+j][n=l15]) ----
  const int gcol = wave * H_DIM + slot * 16 + l15;   // gate row 0..2047
  s16x8 bhh_f[16];
#pragma unroll
  for (int kb = 0; kb < 16; ++kb) {
    const float* src = Whh + (size_t)gcol * H_DIM + kb * 32 + q * 8;
    s16x8 v;
#pragma unroll
    for (int i = 0; i < 8; ++i) v[i] = (short)f2bf(src[i]);
    bhh_f[kb] = v;
  }
  s16x8 bih_f[8];
#pragma unroll
  for (int kb = 0; kb < 8; ++kb) {
    const float* src = Wih + (size_t)gcol * I_DIM + kb * 32 + q * 8;
    s16x8 v;
#pragma unroll
    for (int i = 0; i < 8; ++i) v[i] = (short)f2bf(src[i]);
    bih_f[kb] = v;
  }
  const float bias_v = bih[gcol] + bhh[gcol];

  // ---- x staging helpers: thread covers row m0, cols kc0*16..+15 ----
  const int m0  = tid & 15;          // global: 16 lanes read 16 rows (64B segs)
  const int kc0 = tid >> 4;
  const int xkb   = kc0 >> 1;
  const int laneA = m0 + 32 * (kc0 & 1);   // frag-lane of xt[0..7]
  const int laneB = laneA + 16;            // frag-lane of xt[8..15]

  // ---- preload x tile t=0 into parity 0 ----
  {
    const float* src = x + ((size_t)(g * BC + m0) * S_LEN) * I_DIM + kc0 * 16;
    float xt[16];
    *(float4*)&xt[0]  = ((const float4*)src)[0];
    *(float4*)&xt[4]  = ((const float4*)src)[1];
    *(float4*)&xt[8]  = ((const float4*)src)[2];
    *(float4*)&xt[12] = ((const float4*)src)[3];
    s16x8 v0, v1;
#pragma unroll
    for (int i = 0; i < 8; ++i) { v0[i] = (short)f2bf(xt[i]); v1[i] = (short)f2bf(xt[8 + i]); }
    *(s16x8*)&x_s[0][xkb][laneA * 8] = v0;
    *(s16x8*)&x_s[0][xkb][laneB * 8] = v1;
  }
  __syncthreads();

  int* const     fgrp  = flags + (size_t)g * 32 * FSTRIDE;
  const uint64_t fpoll = (uint64_t)(fgrp + (size_t)(lane & 31) * FSTRIDE);
  const uint64_t fmine = (uint64_t)(fgrp + (size_t)slot * FSTRIDE);

  // producer store coordinates (fragment-order payload)
  const int erow  = wave * 4 + q;                   // batch row this lane owns
  const int kcol  = slot * 16 + l15;                // h column this lane owns
  const int skb   = kcol >> 5;
  const int slane = erow + 16 * ((kcol >> 3) & 3);
  const int sj    = kcol & 7;
  const int sidx  = skb * 512 + slane * 8 + sj;     // within-group short idx

  int p = 0;
  float c_reg = 0.0f;

  for (int t = 0; t < S_LEN; ++t) {
    const bool pf = (t + 1 < S_LEN);

    // ---- issue next x slice (plain loads; 64B segments per lane) ----
    float xt[16];
    if (pf) {
      const float* src = x + ((size_t)(g * BC + m0) * S_LEN + (t + 1)) * I_DIM + kc0 * 16;
      *(float4*)&xt[0]  = ((const float4*)src)[0];
      *(float4*)&xt[4]  = ((const float4*)src)[1];
      *(float4*)&xt[8]  = ((const float4*)src)[2];
      *(float4*)&xt[12] = ((const float4*)src)[3];
    }

    // ---- x-part of gates: conflict-free lane-order LDS reads ----
    f32x4 acc = {bias_v, bias_v, bias_v, bias_v};
#pragma unroll
    for (int kb = 0; kb < 8; ++kb) {
      s16x8 a = *(const s16x8*)&x_s[p][kb][lane * 8];
      acc = __builtin_amdgcn_mfma_f32_16x16x32_bf16(a, bih_f[kb], acc, 0, 0, 0);
    }

    if (t > 0) {
      // ---- wave0 polls the 32 per-CU flags at the TCC ----
      if (wave == 0 && !s_abort) {
        int rounds = 0;
        for (;;) {
          int fv = poll_local(fpoll);
          if (__all(fv >= t)) break;
          if (++rounds > (1 << 15)) { if (lane == 0) s_abort = 1; break; }
        }
      }
      __syncthreads();                               // B1: h_t published
      // ---- A-frags straight from L2 (fragment order, coalesced, rotated) ----
      const unsigned short* pb =
          hpay + (size_t)((t & wmask) * GROUPS + g) * PAYG + lane * 8;
      s16x8 afr[16];
#pragma unroll
      for (int kb = 0; kb < 16; ++kb)
        afr[kb] = *(const s16x8*)(pb + kb * 512);
      f32x4 h0 = {0.f, 0.f, 0.f, 0.f}, h1 = {0.f, 0.f, 0.f, 0.f};
#pragma unroll
      for (int kb = 0; kb < 16; kb += 2) {
        h0 = __builtin_amdgcn_mfma_f32_16x16x32_bf16(afr[kb],     bhh_f[kb],     h0, 0, 0, 0);
        h1 = __builtin_amdgcn_mfma_f32_16x16x32_bf16(afr[kb + 1], bhh_f[kb + 1], h1, 0, 0, 0);
      }
      acc += h0 + h1;
    }

    // ---- publish gate section (C/D: col=l15, row=q*4+r) ----
#pragma unroll
    for (int r = 0; r < 4; ++r) gates[wave][q * 4 + r][l15] = acc[r];
    __syncthreads();                                 // B3: gates ready

    // ---- elementwise; lane owns (row=erow, col=kcol) ----
    {
      float yi = gates[0][erow][l15];
      float yf = gates[1][erow][l15];
      float yg = gates[2][erow][l15];
      float yo = gates[3][erow][l15];
      float ig = sigf(yi), fg = sigf(yf), gg = fmaxf(yg, 0.0f), og = sigf(yo);
      c_reg = fg * c_reg + ig * gg;
      float h = og * c_reg;
      hpay[(size_t)(((t + 1) & wmask) * GROUPS + g) * PAYG + sidx] = f2bf(h);
    }

    // ---- stash prefetched x into other parity (bank-light b128 writes) ----
    if (pf) {
      s16x8 v0, v1;
#pragma unroll
      for (int i = 0; i < 8; ++i) { v0[i] = (short)f2bf(xt[i]); v1[i] = (short)f2bf(xt[8 + i]); }
      *(s16x8*)&x_s[p ^ 1][xkb][laneA * 8] = v0;
      *(s16x8*)&x_s[p ^ 1][xkb][laneB * 8] = v1;
    }

    drain_vm();            // h stores ack'd at the XCD L2
    __syncthreads();       // B4: whole block drained; x_s[p^1] complete
    if (tid == 0) st_flag(fmine, t + 1);
    p ^= 1;
  }

  // ---- final FC by slot-0 block of each group; h_S in rotation slot 0 ----
  if (slot == 0) {
    if (wave == 0 && !s_abort) {
      int rounds = 0;
      for (;;) {
        int fv = poll_local(fpoll);
        if (__all(fv >= S_LEN)) break;
        if (++rounds > (1 << 15)) break;
      }
    }
    __syncthreads();
    // bulk-load group's 16 KB payload (slot 0) and unswizzle into LDS
    unsigned short* hfc = &x_s[0][0][0];             // reuse as [16][512]
    {
      const unsigned short* pb = hpay + (size_t)g * PAYG + (size_t)tid * 32;
      s16x8 c0 = ((const s16x8*)pb)[0];
      s16x8 c1 = ((const s16x8*)pb)[1];
      s16x8 c2 = ((const s16x8*)pb)[2];
      s16x8 c3 = ((const s16x8*)pb)[3];
      const int kb = tid >> 4;
      const int L0 = (tid & 15) * 4;
      s16x8 cc[4] = {c0, c1, c2, c3};
#pragma unroll
      for (int i = 0; i < 4; ++i) {
        const int L = L0 + i;
        const int m = L & 15, qq = L >> 4;
        *(s16x8*)&hfc[m * 512 + kb * 32 + qq * 8] = cc[i];
      }
    }
    __syncthreads();

    if (tid < BC * 10) {
      const int row = tid / 10, o = tid - row * 10;
      const float* wr = fcw + (size_t)o * H_DIM;
      float sum = fcb[o];
      for (int k = 0; k < H_DIM; k += 8) {
#pragma unroll
        for (int j = 0; j < 8; ++j)
          sum += bf2f(hfc[row * 512 + k + j]) * wr[k + j];
      }
      out[(g * BC + row) * 10 + o] = sum;
    }
  }
}

extern "C" void kernel_launch(void* const* d_in, const int* in_sizes, int n_in,
                              void* d_out, int out_size, void* d_ws, size_t ws_size,
                              hipStream_t stream) {
  (void)in_sizes; (void)n_in; (void)out_size;
  const float* x   = (const float*)d_in[0];
  const float* Wih = (const float*)d_in[1];
  const float* Whh = (const float*)d_in[2];
  const float* bih = (const float*)d_in[3];
  const float* bhh = (const float*)d_in[4];
  const float* fcw = (const float*)d_in[5];
  const float* fcb = (const float*)d_in[6];

  int* arrive = (int*)d_ws;                          // @0
  int* table  = (int*)((char*)d_ws + 4096);          // @4K, 512 ints
  int* flags  = (int*)((char*)d_ws + 8192);          // @8K, 16 KB (poison-safe)
  unsigned short* hpay = (unsigned short*)((char*)d_ws + 32768);

  // rotation depth W (power of two, 2..64) sized to the workspace
  size_t avail = ws_size > 32768 ? ws_size - 32768 : 0;
  int W = 2;
  while (W < 64 && (size_t)(W * 2) * (PAYSLOT * 2) <= avail) W <<= 1;

  // arrive must start 0 (table fully overwritten; flag poison is negative)
  hipMemsetAsync(d_ws, 0, 4096, stream);

  hipLaunchKernelGGL(lstm_persistent, dim3(NBLK), dim3(256), 0, stream,
                     x, Wih, Whh, bih, bhh, fcw, fcb, (float*)d_out,
                     arrive, table, flags, hpay, W - 1);
}

// Round 7
// 3679.036 us; speedup vs baseline: 1.6706x; 1.6706x over previous
//
#include <hip/hip_runtime.h>
#include <stdint.h>

// ---------------------------------------------------------------------------
// Persistent-kernel LSTM (relu g-gate, h = o*c, no tanh).
// B=128, S=1024, I=256, H=512, O=10.
//
// R7 = R6 structure + R5's PROVEN freshness mechanism.
//  * 512 blocks; rendezvous publishes (XCC_ID, HW_ID[15:8]); first block per
//    distinct physical CU is the worker -> 8 XCD-pure groups of 32, 1/CU,
//    all 8 XCDs. Fallback rank<32 if CU-key aliases (safe: freshness below
//    does not depend on 1-block-per-CU).
//  * h payload in MFMA-A fragment order, W=16 rotation slots: an address is
//    re-read only after ~512 KB has streamed through the 32 KB vL1
//    (capacity eviction => always-fresh plain loads — the mechanism that
//    passed in R5), while the 256 KB/XCD rotating set stays dirty-resident
//    in the 4 MB L2 (no write-allocate RMW storm — R5's regression).
//    NO buffer_inv (R6's failure: unverified vL1-invalidate semantics).
//  * x pipeline 2 deep: x[t+2] issued at step t, stashed to LDS at t+1.
//  * Flags: producer plain-stores h -> vmcnt(0) -> barrier -> flag store;
//    consumer polls via global_atomic_add(0) sc0 (executes at TCC, fresh).
// ---------------------------------------------------------------------------

#define GROUPS 8
#define BC     16
#define S_LEN  1024
#define I_DIM  256
#define H_DIM  512
#define NBLK   512
#define FSTRIDE 16                    // flag stride in ints (64 B)
#define PAYG   (BC * H_DIM)           // 8192 shorts per group per slot
#define PAYSLOT (GROUPS * PAYG)       // shorts per rotation slot

typedef float f32x4 __attribute__((ext_vector_type(4)));
typedef short s16x8 __attribute__((ext_vector_type(8)));

__device__ __forceinline__ unsigned short f2bf(float f) {
  unsigned u = __float_as_uint(f);
  u += 0x7fffu + ((u >> 16) & 1u);   // RNE
  return (unsigned short)(u >> 16);
}
__device__ __forceinline__ float bf2f(unsigned short h) {
  return __uint_as_float(((unsigned)h) << 16);
}
__device__ __forceinline__ float sigf(float x) { return 1.0f / (1.0f + __expf(-x)); }

__device__ __forceinline__ int poll_local(uint64_t a) {
  int v;
  asm volatile("global_atomic_add %0, %1, %2, off sc0\n\ts_waitcnt vmcnt(0)"
               : "=v"(v) : "v"(a), "v"(0) : "memory");
  return v;
}
__device__ __forceinline__ int ld_sc1(uint64_t a) {
  int v;
  asm volatile("global_load_dword %0, %1, off sc1\n\ts_waitcnt vmcnt(0)"
               : "=v"(v) : "v"(a) : "memory");
  return v;
}
__device__ __forceinline__ void st_sc1(uint64_t a, int v) {
  asm volatile("global_store_dword %0, %1, off sc1" :: "v"(a), "v"(v) : "memory");
}
__device__ __forceinline__ void st_flag(uint64_t a, int v) {
  asm volatile("global_store_dword %0, %1, off" :: "v"(a), "v"(v) : "memory");
}
__device__ __forceinline__ void drain_vm() {
  asm volatile("s_waitcnt vmcnt(0)" ::: "memory");
}

__global__ __launch_bounds__(256, 2)
void lstm_persistent(const float* __restrict__ x,
                     const float* __restrict__ Wih,
                     const float* __restrict__ Whh,
                     const float* __restrict__ bih,
                     const float* __restrict__ bhh,
                     const float* __restrict__ fcw,
                     const float* __restrict__ fcb,
                     float* __restrict__ out,
                     int* __restrict__ arrive,           // [1], zeroed
                     int* __restrict__ table,            // [NBLK]
                     int* __restrict__ flags,            // [GROUPS][32][FSTRIDE]
                     unsigned short* __restrict__ hpay,  // [W][GROUPS][PAYG]
                     int wmask)
{
  __shared__ __align__(16) unsigned short x_s[2][8][512];  // fragment-order x
  __shared__ __align__(16) float gates[4][BC][18];
  __shared__ int tbl[NBLK];
  __shared__ unsigned long long seen[GROUPS][4];
  __shared__ int s_grp, s_slot, s_abort;

  const int tid  = threadIdx.x;
  const int wave = tid >> 6;        // gate section 0..3 (i,f,g,o)
  const int lane = tid & 63;
  const int q    = lane >> 4;
  const int l15  = lane & 15;
  const int bid  = blockIdx.x;

  // ---- rendezvous: publish (xcd, cu-key), wait for all, elect workers ----
  const int xcd = __builtin_amdgcn_s_getreg((31u << 11) | 20) & 7;     // XCC_ID
  const int cuk = __builtin_amdgcn_s_getreg((7u << 11) | (8u << 6) | 4) & 0xff; // HW_ID[15:8]
  if (tid == 0) {
    st_sc1((uint64_t)&table[bid], xcd | (cuk << 3));
    drain_vm();
    atomicAdd(arrive, 1);
    int spins = 0;
    while (atomicAdd(arrive, 0) < NBLK && spins < (1 << 22)) {
      __builtin_amdgcn_s_sleep(8);
      ++spins;
    }
  }
  if (tid < 32) *(unsigned long long*)&seen[tid >> 2][tid & 3] = 0ull;
  __syncthreads();
  tbl[tid]       = ld_sc1((uint64_t)&table[tid]);
  tbl[tid + 256] = ld_sc1((uint64_t)&table[tid + 256]);
  __syncthreads();
  if (tid == 0) {
    int cnt[8]    = {0, 0, 0, 0, 0, 0, 0, 0};
    int wcount[8] = {0, 0, 0, 0, 0, 0, 0, 0};
    int my_rank = 0, my_w = -1;
    for (int j = 0; j < NBLK; ++j) {
      const int e  = tbl[j];
      const int xx = e & 7;
      const int ky = (e >> 3) & 0xff;
      const unsigned long long bit = 1ull << (ky & 63);
      const bool first = !(seen[xx][ky >> 6] & bit);
      if (first) seen[xx][ky >> 6] |= bit;
      int w = -1;
      if (first && wcount[xx] < 32) w = wcount[xx]++;
      if (j == bid) { my_rank = cnt[xx]; my_w = w; }
      cnt[xx]++;
    }
    int slot = my_w;
    if (wcount[xcd] != 32)                 // CU-key aliasing: safe fallback
      slot = (my_rank < 32) ? my_rank : -1;
    s_grp = (slot >= 0) ? xcd : -1;
    s_slot = slot;
    s_abort = 0;
  }
  __syncthreads();
  const int g    = s_grp;
  const int slot = s_slot;
  if (g < 0) return;                       // surplus block exits

  // ---- persistent weight fragments (B-frag: lane holds B[k=q*8+j][n=l15]) ----
  const int gcol = wave * H_DIM + slot * 16 + l15;   // gate row 0..2047
  s16x8 bhh_f[16];
#pragma unroll
  for (int kb = 0; kb < 16; ++kb) {
    const float* src = Whh + (size_t)gcol * H_DIM + kb * 32 + q * 8;
    s16x8 v;
#pragma unroll
    for (int i = 0; i < 8; ++i) v[i] = (short)f2bf(src[i]);
    bhh_f[kb] = v;
  }
  s16x8 bih_f[8];
#pragma unroll
  for (int kb = 0; kb < 8; ++kb) {
    const float* src = Wih + (size_t)gcol * I_DIM + kb * 32 + q * 8;
    s16x8 v;
#pragma unroll
    for (int i = 0; i < 8; ++i) v[i] = (short)f2bf(src[i]);
    bih_f[kb] = v;
  }
  const float bias_v = bih[gcol] + bhh[gcol];

  // ---- x staging geometry: thread covers row m0, cols kc0*16..+15 ----
  const int m0  = tid & 15;
  const int kc0 = tid >> 4;
  const int xkb   = kc0 >> 1;
  const int laneA = m0 + 32 * (kc0 & 1);
  const int laneB = laneA + 16;
  const float* const xrow = x + (size_t)(g * BC + m0) * S_LEN * I_DIM + kc0 * 16;

  // ---- preload: x[0] -> LDS parity 0; x[1] -> regs xN ----
  {
    float xt[16];
    *(float4*)&xt[0]  = ((const float4*)xrow)[0];
    *(float4*)&xt[4]  = ((const float4*)xrow)[1];
    *(float4*)&xt[8]  = ((const float4*)xrow)[2];
    *(float4*)&xt[12] = ((const float4*)xrow)[3];
    s16x8 v0, v1;
#pragma unroll
    for (int i = 0; i < 8; ++i) { v0[i] = (short)f2bf(xt[i]); v1[i] = (short)f2bf(xt[8 + i]); }
    *(s16x8*)&x_s[0][xkb][laneA * 8] = v0;
    *(s16x8*)&x_s[0][xkb][laneB * 8] = v1;
  }
  float xN[16];
  {
    const float* src = xrow + (size_t)1 * I_DIM;
    *(float4*)&xN[0]  = ((const float4*)src)[0];
    *(float4*)&xN[4]  = ((const float4*)src)[1];
    *(float4*)&xN[8]  = ((const float4*)src)[2];
    *(float4*)&xN[12] = ((const float4*)src)[3];
  }
  __syncthreads();

  int* const     fgrp  = flags + (size_t)g * 32 * FSTRIDE;
  const uint64_t fpoll = (uint64_t)(fgrp + (size_t)(lane & 31) * FSTRIDE);
  const uint64_t fmine = (uint64_t)(fgrp + (size_t)slot * FSTRIDE);

  // producer store coordinates (fragment-order payload)
  const int erow  = wave * 4 + q;
  const int kcol  = slot * 16 + l15;
  const int sidx  = (kcol >> 5) * 512 + (erow + 16 * ((kcol >> 3) & 3)) * 8 + (kcol & 7);

  int p = 0;
  float c_reg = 0.0f;

  for (int t = 0; t < S_LEN; ++t) {
    // ---- 1) issue x[t+2] loads (consumed next step: HBM latency hidden) ----
    float xF[16];
    if (t + 2 < S_LEN) {
      const float* src = xrow + (size_t)(t + 2) * I_DIM;
      *(float4*)&xF[0]  = ((const float4*)src)[0];
      *(float4*)&xF[4]  = ((const float4*)src)[1];
      *(float4*)&xF[8]  = ((const float4*)src)[2];
      *(float4*)&xF[12] = ((const float4*)src)[3];
    }

    // ---- 2) x-part of gates from LDS ----
    f32x4 acc = {bias_v, bias_v, bias_v, bias_v};
#pragma unroll
    for (int kb = 0; kb < 8; ++kb) {
      s16x8 a = *(const s16x8*)&x_s[p][kb][lane * 8];
      acc = __builtin_amdgcn_mfma_f32_16x16x32_bf16(a, bih_f[kb], acc, 0, 0, 0);
    }

    // ---- 3) stash xN (= x[t+1], loaded a full step ago) into other parity ----
    if (t + 1 < S_LEN) {
      s16x8 v0, v1;
#pragma unroll
      for (int i = 0; i < 8; ++i) { v0[i] = (short)f2bf(xN[i]); v1[i] = (short)f2bf(xN[8 + i]); }
      *(s16x8*)&x_s[p ^ 1][xkb][laneA * 8] = v0;
      *(s16x8*)&x_s[p ^ 1][xkb][laneB * 8] = v1;
    }

    if (t > 0) {
      // ---- 4) wait for h_t, then load A-frags (rotation slot t & wmask) ----
      if (wave == 0 && !s_abort) {
        int rounds = 0;
        for (;;) {
          int fv = poll_local(fpoll);
          if (__all(fv >= t)) break;
          if (++rounds > (1 << 15)) { if (lane == 0) s_abort = 1; break; }
        }
      }
      __syncthreads();                             // B1: h_t published
      const unsigned short* pb =
          hpay + (size_t)((t & wmask) * GROUPS + g) * PAYG + lane * 8;
      s16x8 afr[16];
#pragma unroll
      for (int kb = 0; kb < 16; ++kb)
        afr[kb] = *(const s16x8*)(pb + kb * 512);
      f32x4 h0 = {0.f, 0.f, 0.f, 0.f}, h1 = {0.f, 0.f, 0.f, 0.f};
#pragma unroll
      for (int kb = 0; kb < 16; kb += 2) {
        h0 = __builtin_amdgcn_mfma_f32_16x16x32_bf16(afr[kb],     bhh_f[kb],     h0, 0, 0, 0);
        h1 = __builtin_amdgcn_mfma_f32_16x16x32_bf16(afr[kb + 1], bhh_f[kb + 1], h1, 0, 0, 0);
      }
      acc += h0 + h1;
    }

    // ---- 5) publish gate section (C/D: col=l15, row=q*4+r) ----
#pragma unroll
    for (int r = 0; r < 4; ++r) gates[wave][q * 4 + r][l15] = acc[r];
    __syncthreads();                               // B3: gates ready

    // ---- 6) elementwise; lane owns (row=erow, col=kcol); store h_{t+1} ----
    {
      float yi = gates[0][erow][l15];
      float yf = gates[1][erow][l15];
      float yg = gates[2][erow][l15];
      float yo = gates[3][erow][l15];
      float ig = sigf(yi), fg = sigf(yf), gg = fmaxf(yg, 0.0f), og = sigf(yo);
      c_reg = fg * c_reg + ig * gg;
      float h = og * c_reg;
      hpay[(size_t)(((t + 1) & wmask) * GROUPS + g) * PAYG + sidx] = f2bf(h);
    }

    // ---- 7) drain stores, then flag ----
    drain_vm();
    __syncthreads();                               // B4: block fully drained
    if (tid == 0) st_flag(fmine, t + 1);

    // ---- 8) advance pipeline ----
#pragma unroll
    for (int i = 0; i < 16; ++i) xN[i] = xF[i];
    p ^= 1;
  }

  // ---- final FC by slot-0 block; h_S in slot (S_LEN & wmask) == 0 ----
  if (slot == 0) {
    if (wave == 0 && !s_abort) {
      int rounds = 0;
      for (;;) {
        int fv = poll_local(fpoll);
        if (__all(fv >= S_LEN)) break;
        if (++rounds > (1 << 15)) break;
      }
    }
    __syncthreads();
    unsigned short* hfc = &x_s[0][0][0];           // reuse as [16][512]
    {
      const unsigned short* pb = hpay + (size_t)g * PAYG + (size_t)tid * 32;
      s16x8 cc[4];
      cc[0] = ((const s16x8*)pb)[0];
      cc[1] = ((const s16x8*)pb)[1];
      cc[2] = ((const s16x8*)pb)[2];
      cc[3] = ((const s16x8*)pb)[3];
      const int kb = tid >> 4;
      const int L0 = (tid & 15) * 4;
#pragma unroll
      for (int i = 0; i < 4; ++i) {
        const int L = L0 + i;
        const int m = L & 15, qq = L >> 4;
        *(s16x8*)&hfc[m * 512 + kb * 32 + qq * 8] = cc[i];
      }
    }
    __syncthreads();

    if (tid < BC * 10) {
      const int row = tid / 10, o = tid - row * 10;
      const float* wr = fcw + (size_t)o * H_DIM;
      float sum = fcb[o];
      for (int k = 0; k < H_DIM; k += 8) {
#pragma unroll
        for (int j = 0; j < 8; ++j)
          sum += bf2f(hfc[row * 512 + k + j]) * wr[k + j];
      }
      out[(g * BC + row) * 10 + o] = sum;
    }
  }
}

extern "C" void kernel_launch(void* const* d_in, const int* in_sizes, int n_in,
                              void* d_out, int out_size, void* d_ws, size_t ws_size,
                              hipStream_t stream) {
  (void)in_sizes; (void)n_in; (void)out_size;
  const float* x   = (const float*)d_in[0];
  const float* Wih = (const float*)d_in[1];
  const float* Whh = (const float*)d_in[2];
  const float* bih = (const float*)d_in[3];
  const float* bhh = (const float*)d_in[4];
  const float* fcw = (const float*)d_in[5];
  const float* fcb = (const float*)d_in[6];

  int* arrive = (int*)d_ws;                          // @0
  int* table  = (int*)((char*)d_ws + 4096);          // @4K, 512 ints
  int* flags  = (int*)((char*)d_ws + 8192);          // @8K (poison negative = safe)
  unsigned short* hpay = (unsigned short*)((char*)d_ws + 32768);

  // rotation depth W: power of two, 2..16 (16 => ~512 KB L1 turnover per
  // address reuse, yet only 256 KB resident per XCD L2)
  size_t avail = ws_size > 32768 ? ws_size - 32768 : 0;
  int W = 2;
  while (W < 16 && (size_t)(W * 2) * (PAYSLOT * 2) <= avail) W <<= 1;

  hipMemsetAsync(d_ws, 0, 4096, stream);             // arrive = 0

  hipLaunchKernelGGL(lstm_persistent, dim3(NBLK), dim3(256), 0, stream,
                     x, Wih, Whh, bih, bhh, fcw, fcb, (float*)d_out,
                     arrive, table, flags, hpay, W - 1);
}